// Round 19
// baseline (171.395 us; speedup 1.0000x reference)
//
#include <hip/hip_runtime.h>
#include <hip/hip_bf16.h>
#include <stdint.h>

// RGCN (basis decomposition, mean agg, root weight + bias)
// r19: CROSS-NODE pipelining in k_fused phase 1. With mean deg=16 the
// within-node loop barely runs; per-node prologue latency (csr s_load wait +
// first-gather LLC ~600cy) was exposed ~100K times. Now: after a node's
// steady loop, grab the NEXT node and issue its first 8 csr+gathers BEFORE
// consuming the current node's 16-entry tail + fl writes -> prologue hides
// under tail work. Build chain unchanged from r18 (merged prep+scatter,
// pad-only bsort fill).

#define FPAD 1160     // LDS feat row stride in bf16
#define SCAT_CH 8192  // edges per scatter block
#define PADV 16       // pad csr entry: (src=0)<<5 | et=16
#define BKCAP 2560    // brec slots per bucket (mean 2048, +11 sigma)
#define CSTRIDE 3584  // csr slots per bucket (max padded 3456 + 24 over-read)

typedef __attribute__((ext_vector_type(8))) __bf16 bf16x8;
typedef __attribute__((ext_vector_type(4))) float f32x4;
typedef __attribute__((ext_vector_type(2))) float f32x2;

#define RFL(v) __builtin_amdgcn_readfirstlane(v)

// --- K1: MERGED prep + bucket scatter --------------------------------------
__global__ __launch_bounds__(256) void k_ps(const float* __restrict__ x,
                                            uint8_t* __restrict__ xq,
                                            __hip_bfloat16* __restrict__ xb, int n4,
                                            const float* __restrict__ W,
                                            __hip_bfloat16* __restrict__ Wf,
                                            const float* __restrict__ comp,
                                            float* __restrict__ comp17,
                                            const int* __restrict__ src,
                                            const int* __restrict__ dst,
                                            const int* __restrict__ et,
                                            int E, int NB,
                                            int* __restrict__ cursor,
                                            int* __restrict__ brec,
                                            int scB, int xbB, int wpB) {
    extern __shared__ int sm[];   // [NB] cnt, [NB] gbase (scatter blocks only)
    int b = blockIdx.x;
    if (b < scB) {
        int* cnt = sm;
        int* gb  = sm + NB;
        for (int i = threadIdx.x; i < NB; i += 256) cnt[i] = 0;
        __syncthreads();
        int e0 = b * SCAT_CH;
        int e1 = min(e0 + SCAT_CH, E);
        for (int e = e0 + threadIdx.x; e < e1; e += 256)
            atomicAdd(&cnt[dst[e] >> 7], 1);
        __syncthreads();
        for (int i = threadIdx.x; i < NB; i += 256) {
            int c = cnt[i];
            gb[i] = c ? atomicAdd(&cursor[i], c) : 0;
        }
        __syncthreads();
        for (int i = threadIdx.x; i < NB; i += 256) cnt[i] = 0;
        __syncthreads();
        for (int e = e0 + threadIdx.x; e < e1; e += 256) {
            int d = dst[e];
            int bk = d >> 7;
            int off = gb[bk] + atomicAdd(&cnt[bk], 1);
            if (off < BKCAP)
                brec[bk * BKCAP + off] = (src[e] << 11) | ((d & 127) << 4) | (et[e] & 15);
        }
    } else if (b < scB + xbB) {
        int i = (b - scB) * 256 + threadIdx.x;
        if (i < n4) {
            float4 v = ((const float4*)x)[i];
            uint32_t q = __builtin_amdgcn_cvt_pk_fp8_f32(v.x, v.y, 0u, 0);
            q = __builtin_amdgcn_cvt_pk_fp8_f32(v.z, v.w, q, 1);
            ((uint32_t*)xq)[i] = q;
            __hip_bfloat16 h0 = __float2bfloat16(v.x), h1 = __float2bfloat16(v.y);
            __hip_bfloat16 h2 = __float2bfloat16(v.z), h3 = __float2bfloat16(v.w);
            uint32_t p0 = ((uint32_t)*(uint16_t*)&h1 << 16) | *(uint16_t*)&h0;
            uint32_t p1 = ((uint32_t)*(uint16_t*)&h3 << 16) | *(uint16_t*)&h2;
            ((uint2*)xb)[i] = make_uint2(p0, p1);
        }
    } else if (b < scB + xbB + wpB) {
        int idx = (b - scB - xbB) * 256 + threadIdx.x;
        if (idx < 1152 * 128) {
            int k = idx >> 7, n = idx & 127;
            int kb = k >> 5, hi = (k >> 3) & 3, j = k & 7;
            Wf[((((kb << 2) + hi) << 7 | n) << 3) | j] = __float2bfloat16(W[idx]);
        }
    } else {
        int t = threadIdx.x;
        if (t < 136) comp17[t] = (t < 128) ? comp[t] : 0.f;  // row 16 = zeros
    }
}

// --- K2: per-bucket counting sort -> PADDED csr + rps/dga ------------------
__global__ __launch_bounds__(256) void k_bsort(const int* __restrict__ brec,
                                               const int* __restrict__ cursor,
                                               int N,
                                               int* __restrict__ rps,
                                               int* __restrict__ dga,
                                               int* __restrict__ csr) {
    __shared__ int cnt[128], st[128];
    int b = blockIdx.x;
    int ne = min(cursor[b], BKCAP);
    int rbase = b * BKCAP;
    int pbase = b * CSTRIDE;
    int t = threadIdx.x;
    if (t < 128) cnt[t] = 0;
    __syncthreads();
    for (int i = t; i < ne; i += 256)
        atomicAdd(&cnt[(brec[rbase + i] >> 4) & 127], 1);
    __syncthreads();
    if (t < 128) st[t] = (cnt[t] + 7) & ~7;   // padded counts
    __syncthreads();
    for (int off = 1; off < 128; off <<= 1) {
        int u = 0;
        if (t < 128 && t >= off) u = st[t - off];
        __syncthreads();
        if (t < 128) st[t] += u;
        __syncthreads();
    }
    if (t < 128) {
        int c = cnt[t];
        int pc = (c + 7) & ~7;
        int pexcl = st[t] - pc;
        int d = b * 128 + t;
        if (d < N) { rps[d] = pbase + pexcl; dga[d] = c; }
        for (int k = c; k < pc; k++) csr[pbase + pexcl + k] = PADV;
        cnt[t] = pexcl;   // running cursor (offset in padded region)
    } else if (t >= 128 && t < 152) {
        int idx = st[127] + (t - 128);
        if (idx < CSTRIDE) csr[pbase + idx] = PADV;
    }
    __syncthreads();
    for (int i = t; i < ne; i += 256) {
        int r = brec[rbase + i];
        int d7 = (r >> 4) & 127;
        int off = atomicAdd(&cnt[d7], 1);
        csr[pbase + off] = ((r >> 11) << 5) | (r & 15);   // src<<5 | et5
    }
}

// uniform fp8 gather: pp wave-uniform; lane reads ushort (channels 2l,2l+1)
#define GATH(pp) ((uint32_t)xq16[(uint32_t)((pp) >> 5) * 64u + (uint32_t)lane])

// consume one edge: fp8 decode (2 x v_cvt_f32_fp8) + packed-f32 FMA
// (pad entries hit comp17 row 16 = zeros -> numerically a no-op)
#define CONS1(pp, raw) do {                                               \
    uint32_t _r = (raw);                                                  \
    float _x0 = __builtin_amdgcn_cvt_f32_fp8(_r, 0);                      \
    float _x1 = __builtin_amdgcn_cvt_f32_fp8(_r, 1);                      \
    const f32x2* _cf = (const f32x2*)(comp17 + ((pp) & 31) * 8);          \
    f32x2 _xx0 = (f32x2){_x0, _x0};                                       \
    f32x2 _xx1 = (f32x2){_x1, _x1};                                       \
    f32x2 _c0 = _cf[0], _c1 = _cf[1], _c2 = _cf[2], _c3 = _cf[3];         \
    a0[0] += _c0 * _xx0; a0[1] += _c1 * _xx0;                             \
    a0[2] += _c2 * _xx0; a0[3] += _c3 * _xx0;                             \
    a1[0] += _c0 * _xx1; a1[1] += _c1 * _xx1;                             \
    a1[2] += _c2 * _xx1; a1[3] += _c3 * _xx1;                             \
} while (0)

#define GRAB(lrv) do { int _g = 0; if (lane == 0) _g = atomicAdd(&snext, 1); \
                       lrv = RFL(__shfl(_g, 0)); } while (0)

// --- K3: FUSED aggregation + MFMA GEMM -------------------------------------
// Block = 16 nodes, 512 thr = 8 waves. Phase 1: dynamic node grab with
// CROSS-NODE pipelining: next node's first 8 csr+gathers issue before the
// current node's tail CONS + fl writes. Within-node: 16-deep over padded
// rows. Phase 2: 16x1152 @ 1152x128 MFMA, 2-deep prefetch.
__global__ __launch_bounds__(512, 8) void k_fused(const uint8_t* __restrict__ xq,
                                                  const __hip_bfloat16* __restrict__ xb,
                                                  const float* __restrict__ comp17,
                                                  const int* __restrict__ rps,
                                                  const int* __restrict__ dga,
                                                  const int* __restrict__ csr,
                                                  const __hip_bfloat16* __restrict__ Wf,
                                                  const float* __restrict__ bias,
                                                  float* __restrict__ out, int M) {
    __shared__ __hip_bfloat16 fl[16][FPAD];
    __shared__ int snext;
    const uint16_t* __restrict__ xq16 = (const uint16_t*)xq;
    const uint32_t* __restrict__ xb32 = (const uint32_t*)xb;
    int t = threadIdx.x;
    int wid = t >> 6, lane = t & 63;
    int i0 = blockIdx.x * 16;
    if (t == 0) snext = 0;
    __syncthreads();

    // ---- phase 1: first grab + full 16-deep prologue ----
    int lr;
    GRAB(lr);
    int iu = 0, s0 = 0, dg = 0;
    int p0 = PADV, p1 = PADV, p2 = PADV, p3 = PADV;
    int p4 = PADV, p5 = PADV, p6 = PADV, p7 = PADV;
    int q0 = PADV, q1 = PADV, q2 = PADV, q3 = PADV;
    int q4 = PADV, q5 = PADV, q6 = PADV, q7 = PADV;
    uint32_t w0 = 0, w1 = 0, w2 = 0, w3 = 0, w4 = 0, w5 = 0, w6 = 0, w7 = 0;
    uint32_t v0 = 0, v1 = 0, v2 = 0, v3 = 0, v4 = 0, v5 = 0, v6 = 0, v7 = 0;
    if (lr < 16) {
        iu = i0 + lr;
        if (iu < M) { s0 = RFL(rps[iu]); dg = RFL(dga[iu]); }
        p0 = RFL(csr[s0]);     p1 = RFL(csr[s0 + 1]);
        p2 = RFL(csr[s0 + 2]); p3 = RFL(csr[s0 + 3]);
        p4 = RFL(csr[s0 + 4]); p5 = RFL(csr[s0 + 5]);
        p6 = RFL(csr[s0 + 6]); p7 = RFL(csr[s0 + 7]);
        w0 = GATH(p0); w1 = GATH(p1); w2 = GATH(p2); w3 = GATH(p3);
        w4 = GATH(p4); w5 = GATH(p5); w6 = GATH(p6); w7 = GATH(p7);
        q0 = RFL(csr[s0 + 8]);  q1 = RFL(csr[s0 + 9]);
        q2 = RFL(csr[s0 + 10]), q3 = RFL(csr[s0 + 11]);
        q4 = RFL(csr[s0 + 12]); q5 = RFL(csr[s0 + 13]);
        q6 = RFL(csr[s0 + 14]); q7 = RFL(csr[s0 + 15]);
        v0 = GATH(q0); v1 = GATH(q1); v2 = GATH(q2); v3 = GATH(q3);
        v4 = GATH(q4); v5 = GATH(q5); v6 = GATH(q6); v7 = GATH(q7);
    }

    #pragma unroll 1
    while (lr < 16) {
        f32x2 a0[4], a1[4];
        #pragma unroll
        for (int b = 0; b < 4; b++) { a0[b] = (f32x2){0.f, 0.f}; a1[b] = (f32x2){0.f, 0.f}; }
        int plen = (dg + 7) & ~7;
        int s1 = s0 + plen;
        int jj = s0;

        // steady loop (only when plen > 16)
        #pragma unroll 1
        while (jj + 16 < s1) {
            int r0 = RFL(csr[jj + 16]), r1 = RFL(csr[jj + 17]);
            int r2 = RFL(csr[jj + 18]), r3 = RFL(csr[jj + 19]);
            int r4 = RFL(csr[jj + 20]), r5 = RFL(csr[jj + 21]);
            int r6 = RFL(csr[jj + 22]), r7 = RFL(csr[jj + 23]);
            uint32_t u0 = GATH(r0), u1 = GATH(r1), u2 = GATH(r2), u3 = GATH(r3);
            uint32_t u4 = GATH(r4), u5 = GATH(r5), u6 = GATH(r6), u7 = GATH(r7);
            CONS1(p0, w0); CONS1(p1, w1); CONS1(p2, w2); CONS1(p3, w3);
            CONS1(p4, w4); CONS1(p5, w5); CONS1(p6, w6); CONS1(p7, w7);
            p0 = q0; p1 = q1; p2 = q2; p3 = q3;
            p4 = q4; p5 = q5; p6 = q6; p7 = q7;
            w0 = v0; w1 = v1; w2 = v2; w3 = v3;
            w4 = v4; w5 = v5; w6 = v6; w7 = v7;
            q0 = r0; q1 = r1; q2 = r2; q3 = r3;
            q4 = r4; q5 = r5; q6 = r6; q7 = r7;
            v0 = u0; v1 = u1; v2 = u2; v3 = u3;
            v4 = u4; v5 = u5; v6 = u6; v7 = u7;
            jj += 8;
        }

        // EARLY GRAB: next node's meta + first 8 csr + 8 gathers issue now,
        // hiding their latency under the tail CONS + finalize below.
        int lrn;
        GRAB(lrn);
        int iun = 0, s0n = 0, dgn = 0;
        int pn0 = PADV, pn1 = PADV, pn2 = PADV, pn3 = PADV;
        int pn4 = PADV, pn5 = PADV, pn6 = PADV, pn7 = PADV;
        uint32_t wn0 = 0, wn1 = 0, wn2 = 0, wn3 = 0;
        uint32_t wn4 = 0, wn5 = 0, wn6 = 0, wn7 = 0;
        if (lrn < 16) {
            iun = i0 + lrn;
            if (iun < M) { s0n = RFL(rps[iun]); dgn = RFL(dga[iun]); }
            pn0 = RFL(csr[s0n]);     pn1 = RFL(csr[s0n + 1]);
            pn2 = RFL(csr[s0n + 2]); pn3 = RFL(csr[s0n + 3]);
            pn4 = RFL(csr[s0n + 4]); pn5 = RFL(csr[s0n + 5]);
            pn6 = RFL(csr[s0n + 6]); pn7 = RFL(csr[s0n + 7]);
            wn0 = GATH(pn0); wn1 = GATH(pn1); wn2 = GATH(pn2); wn3 = GATH(pn3);
            wn4 = GATH(pn4); wn5 = GATH(pn5); wn6 = GATH(pn6); wn7 = GATH(pn7);
        }

        // exact tail for current node (remaining 8 or 16; pads are no-ops
        // numerically but dg==0 rows alias the next node's entries -> guard)
        if (dg > 0) {
            CONS1(p0, w0); CONS1(p1, w1); CONS1(p2, w2); CONS1(p3, w3);
            CONS1(p4, w4); CONS1(p5, w5); CONS1(p6, w6); CONS1(p7, w7);
            if (jj + 8 < s1) {
                CONS1(q0, v0); CONS1(q1, v1); CONS1(q2, v2); CONS1(q3, v3);
                CONS1(q4, v4); CONS1(q5, v5); CONS1(q6, v6); CONS1(q7, v7);
            }
        }

        // finalize current node
        float inv = 1.0f / fmaxf((float)dg, 1.0f);
        #pragma unroll
        for (int b = 0; b < 8; b++) {
            __hip_bfloat16 h0 = __float2bfloat16(a0[b >> 1][b & 1] * inv);
            __hip_bfloat16 h1 = __float2bfloat16(a1[b >> 1][b & 1] * inv);
            uint32_t pk = ((uint32_t)*(uint16_t*)&h1 << 16) | *(uint16_t*)&h0;
            *(uint32_t*)&fl[lr][b * 128 + lane * 2] = pk;
        }
        uint32_t rr = (iu < M) ? xb32[(uint32_t)iu * 64u + lane] : 0u;
        *(uint32_t*)&fl[lr][1024 + lane * 2] = rr;

        // rotate to next node; issue its second prologue half
        lr = lrn; iu = iun; s0 = s0n; dg = dgn;
        if (lr < 16) {
            p0 = pn0; p1 = pn1; p2 = pn2; p3 = pn3;
            p4 = pn4; p5 = pn5; p6 = pn6; p7 = pn7;
            w0 = wn0; w1 = wn1; w2 = wn2; w3 = wn3;
            w4 = wn4; w5 = wn5; w6 = wn6; w7 = wn7;
            q0 = RFL(csr[s0 + 8]);  q1 = RFL(csr[s0 + 9]);
            q2 = RFL(csr[s0 + 10]); q3 = RFL(csr[s0 + 11]);
            q4 = RFL(csr[s0 + 12]); q5 = RFL(csr[s0 + 13]);
            q6 = RFL(csr[s0 + 14]); q7 = RFL(csr[s0 + 15]);
            v0 = GATH(q0); v1 = GATH(q1); v2 = GATH(q2); v3 = GATH(q3);
            v4 = GATH(q4); v5 = GATH(q5); v6 = GATH(q6); v7 = GATH(q7);
        }
    }

    // ---- phase 2: MFMA, 2-deep prefetch; wave wid owns col-tile wid ----
    int lo = lane & 15, hi = lane >> 4;
    int wcol = wid * 16 + lo;
    const bf16x8* wv = (const bf16x8*)Wf;
    // B/bias don't depend on fl: issue before the barrier
    bf16x8 bA = wv[(hi << 7) + wcol];
    bf16x8 bB = wv[(((1 << 2) + hi) << 7) + wcol];
    float bs = bias[wcol];
    __syncthreads();

    f32x4 acc = (f32x4){0.f, 0.f, 0.f, 0.f};
    bf16x8 aA = *(const bf16x8*)&fl[lo][hi * 8];
    bf16x8 aB = *(const bf16x8*)&fl[lo][32 + hi * 8];
    #pragma unroll 4
    for (int kb = 0; kb < 34; kb++) {
        bf16x8 aN = *(const bf16x8*)&fl[lo][(kb + 2) * 32 + hi * 8];
        bf16x8 bN = wv[((((kb + 2) << 2) + hi) << 7) + wcol];
        acc = __builtin_amdgcn_mfma_f32_16x16x32_bf16(aA, bA, acc, 0, 0, 0);
        aA = aB; bA = bB; aB = aN; bB = bN;
    }
    acc = __builtin_amdgcn_mfma_f32_16x16x32_bf16(aA, bA, acc, 0, 0, 0);
    acc = __builtin_amdgcn_mfma_f32_16x16x32_bf16(aB, bB, acc, 0, 0, 0);

    #pragma unroll
    for (int q = 0; q < 4; q++) {
        int row = i0 + hi * 4 + q;   // C/D: col=lane&15, row=(lane>>4)*4+q
        if (row < M)
            out[(size_t)row * 128 + wcol] = acc[q] + bs;
    }
}

extern "C" void kernel_launch(void* const* d_in, const int* in_sizes, int n_in,
                              void* d_out, int out_size, void* d_ws, size_t ws_size,
                              hipStream_t stream) {
    const float* x      = (const float*)d_in[0];   // [N,128]
    const float* weight = (const float*)d_in[1];   // [9,128,128] = [1152,128]
    const float* comp   = (const float*)d_in[2];   // [16,8]
    const float* bias   = (const float*)d_in[3];   // [128]
    const int*   eidx   = (const int*)d_in[4];     // [2,E]
    const int*   etype  = (const int*)d_in[5];     // [E]

    int N = in_sizes[0] / 128;
    int E = in_sizes[5];
    const int* srcA = eidx;
    const int* dstA = eidx + E;
    int NB = (N + 127) >> 7;                       // buckets of 128 dsts

    uint8_t* ws = (uint8_t*)d_ws;
    size_t off = 0;
    auto take = [&](size_t bytes) -> void* {
        void* p = ws + off;
        off = (off + bytes + 255) & ~(size_t)255;
        return p;
    };
    uint8_t* xq        = (uint8_t*)take((size_t)N * 128);
    __hip_bfloat16* xb = (__hip_bfloat16*)take((size_t)N * 128 * sizeof(__hip_bfloat16));
    __hip_bfloat16* Wf = (__hip_bfloat16*)take((size_t)1152 * 128 * sizeof(__hip_bfloat16));
    float* comp17 = (float*)take(136 * sizeof(float));
    int* rps     = (int*)take((size_t)N * sizeof(int));
    int* dga     = (int*)take((size_t)N * sizeof(int));
    int* cursor  = (int*)take((size_t)NB * sizeof(int));
    int* brec    = (int*)take((size_t)NB * BKCAP * sizeof(int));
    int* csr     = (int*)take((size_t)NB * CSTRIDE * sizeof(int));
    (void)ws_size;

    int n4 = N * 128 / 4;
    int xbB = (n4 + 255) / 256;
    int wpB = (1152 * 128 + 255) / 256;
    int scB = (E + SCAT_CH - 1) / SCAT_CH;

    hipMemsetAsync(cursor, 0, (size_t)NB * sizeof(int), stream);
    k_ps<<<scB + xbB + wpB + 1, 256, 2 * NB * sizeof(int), stream>>>(
        x, xq, xb, n4, weight, Wf, comp, comp17,
        srcA, dstA, etype, E, NB, cursor, brec, scB, xbB, wpB);
    k_bsort<<<NB, 256, 0, stream>>>(brec, cursor, N, rps, dga, csr);
    k_fused<<<(N + 15) / 16, 512, 0, stream>>>(xq, xb, comp17, rps, dga, csr,
                                               Wf, bias, (float*)d_out, N);
}

// Round 20
// 169.549 us; speedup vs baseline: 1.0109x; 1.0109x over previous
//
#include <hip/hip_runtime.h>
#include <hip/hip_bf16.h>
#include <stdint.h>

// RGCN (basis decomposition, mean agg, root weight + bias)
// r20 = r18 revert (best measured: 170.4 us). r19's cross-node pipelining
// regressed (-3% on k_fused): the engine is at an issue/latency equilibrium
// where added machinery loses. Full neighborhood tested: shallower/deeper
// pipeline, occupancy up/down, bigger fusion, f32 root, VALU trims, traffic
// halving, cross-node SWP -- all worse or neutral.
// Structure: merged prep+scatter -> per-bucket counting sort (padded csr)
// -> fused (3-stage 16-deep fp8-gather agg -> LDS -> bf16 MFMA GEMM).

#define FPAD 1160     // LDS feat row stride in bf16
#define SCAT_CH 8192  // edges per scatter block
#define PADV 16       // pad csr entry: (src=0)<<5 | et=16
#define BKCAP 2560    // brec slots per bucket (mean 2048, +11 sigma)
#define CSTRIDE 3584  // csr slots per bucket (max padded 3456 + 24 over-read)

typedef __attribute__((ext_vector_type(8))) __bf16 bf16x8;
typedef __attribute__((ext_vector_type(4))) float f32x4;
typedef __attribute__((ext_vector_type(2))) float f32x2;

#define RFL(v) __builtin_amdgcn_readfirstlane(v)

// --- K1: MERGED prep + bucket scatter --------------------------------------
// Grid layout: [0, scB) scatter | [scB, scB+xbB) xq/xb cast |
//              [.., +wpB) Wf pack | last block comp17.
// record = (src<<11) | (dst&127)<<4 | et4; bucket b region = brec + b*BKCAP
__global__ __launch_bounds__(256) void k_ps(const float* __restrict__ x,
                                            uint8_t* __restrict__ xq,
                                            __hip_bfloat16* __restrict__ xb, int n4,
                                            const float* __restrict__ W,
                                            __hip_bfloat16* __restrict__ Wf,
                                            const float* __restrict__ comp,
                                            float* __restrict__ comp17,
                                            const int* __restrict__ src,
                                            const int* __restrict__ dst,
                                            const int* __restrict__ et,
                                            int E, int NB,
                                            int* __restrict__ cursor,
                                            int* __restrict__ brec,
                                            int scB, int xbB, int wpB) {
    extern __shared__ int sm[];   // [NB] cnt, [NB] gbase (scatter blocks only)
    int b = blockIdx.x;
    if (b < scB) {
        int* cnt = sm;
        int* gb  = sm + NB;
        for (int i = threadIdx.x; i < NB; i += 256) cnt[i] = 0;
        __syncthreads();
        int e0 = b * SCAT_CH;
        int e1 = min(e0 + SCAT_CH, E);
        for (int e = e0 + threadIdx.x; e < e1; e += 256)
            atomicAdd(&cnt[dst[e] >> 7], 1);
        __syncthreads();
        for (int i = threadIdx.x; i < NB; i += 256) {
            int c = cnt[i];
            gb[i] = c ? atomicAdd(&cursor[i], c) : 0;
        }
        __syncthreads();
        for (int i = threadIdx.x; i < NB; i += 256) cnt[i] = 0;
        __syncthreads();
        for (int e = e0 + threadIdx.x; e < e1; e += 256) {
            int d = dst[e];
            int bk = d >> 7;
            int off = gb[bk] + atomicAdd(&cnt[bk], 1);
            if (off < BKCAP)
                brec[bk * BKCAP + off] = (src[e] << 11) | ((d & 127) << 4) | (et[e] & 15);
        }
    } else if (b < scB + xbB) {
        int i = (b - scB) * 256 + threadIdx.x;
        if (i < n4) {
            float4 v = ((const float4*)x)[i];
            uint32_t q = __builtin_amdgcn_cvt_pk_fp8_f32(v.x, v.y, 0u, 0);
            q = __builtin_amdgcn_cvt_pk_fp8_f32(v.z, v.w, q, 1);
            ((uint32_t*)xq)[i] = q;
            __hip_bfloat16 h0 = __float2bfloat16(v.x), h1 = __float2bfloat16(v.y);
            __hip_bfloat16 h2 = __float2bfloat16(v.z), h3 = __float2bfloat16(v.w);
            uint32_t p0 = ((uint32_t)*(uint16_t*)&h1 << 16) | *(uint16_t*)&h0;
            uint32_t p1 = ((uint32_t)*(uint16_t*)&h3 << 16) | *(uint16_t*)&h2;
            ((uint2*)xb)[i] = make_uint2(p0, p1);
        }
    } else if (b < scB + xbB + wpB) {
        int idx = (b - scB - xbB) * 256 + threadIdx.x;
        if (idx < 1152 * 128) {
            int k = idx >> 7, n = idx & 127;
            int kb = k >> 5, hi = (k >> 3) & 3, j = k & 7;
            Wf[((((kb << 2) + hi) << 7 | n) << 3) | j] = __float2bfloat16(W[idx]);
        }
    } else {
        int t = threadIdx.x;
        if (t < 136) comp17[t] = (t < 128) ? comp[t] : 0.f;  // row 16 = zeros
    }
}

// --- K2: per-bucket counting sort -> PADDED csr + rps/dga ------------------
// Writes each real entry once; fills ONLY pad slots (<=7 per node + 24 tail).
__global__ __launch_bounds__(256) void k_bsort(const int* __restrict__ brec,
                                               const int* __restrict__ cursor,
                                               int N,
                                               int* __restrict__ rps,
                                               int* __restrict__ dga,
                                               int* __restrict__ csr) {
    __shared__ int cnt[128], st[128];
    int b = blockIdx.x;
    int ne = min(cursor[b], BKCAP);
    int rbase = b * BKCAP;
    int pbase = b * CSTRIDE;
    int t = threadIdx.x;
    if (t < 128) cnt[t] = 0;
    __syncthreads();
    for (int i = t; i < ne; i += 256)
        atomicAdd(&cnt[(brec[rbase + i] >> 4) & 127], 1);
    __syncthreads();
    if (t < 128) st[t] = (cnt[t] + 7) & ~7;   // padded counts
    __syncthreads();
    for (int off = 1; off < 128; off <<= 1) {
        int u = 0;
        if (t < 128 && t >= off) u = st[t - off];
        __syncthreads();
        if (t < 128) st[t] += u;
        __syncthreads();
    }
    if (t < 128) {
        int c = cnt[t];
        int pc = (c + 7) & ~7;
        int pexcl = st[t] - pc;
        int d = b * 128 + t;
        if (d < N) { rps[d] = pbase + pexcl; dga[d] = c; }
        // fill only this node's pad slots [c, pc)
        for (int k = c; k < pc; k++) csr[pbase + pexcl + k] = PADV;
        cnt[t] = pexcl;   // running cursor (offset in padded region)
    } else if (t >= 128 && t < 152) {
        // bucket tail pad for pipeline over-read
        int idx = st[127] + (t - 128);
        if (idx < CSTRIDE) csr[pbase + idx] = PADV;
    }
    __syncthreads();
    for (int i = t; i < ne; i += 256) {
        int r = brec[rbase + i];
        int d7 = (r >> 4) & 127;
        int off = atomicAdd(&cnt[d7], 1);
        csr[pbase + off] = ((r >> 11) << 5) | (r & 15);   // src<<5 | et5
    }
}

// uniform fp8 gather: pp wave-uniform; lane reads ushort (channels 2l,2l+1)
#define GATH(pp) ((uint32_t)xq16[(uint32_t)((pp) >> 5) * 64u + (uint32_t)lane])

// consume one edge: fp8 decode (2 x v_cvt_f32_fp8) + packed-f32 FMA
#define CONS1(pp, raw) do {                                               \
    uint32_t _r = (raw);                                                  \
    float _x0 = __builtin_amdgcn_cvt_f32_fp8(_r, 0);                      \
    float _x1 = __builtin_amdgcn_cvt_f32_fp8(_r, 1);                      \
    const f32x2* _cf = (const f32x2*)(comp17 + ((pp) & 31) * 8);          \
    f32x2 _xx0 = (f32x2){_x0, _x0};                                       \
    f32x2 _xx1 = (f32x2){_x1, _x1};                                       \
    f32x2 _c0 = _cf[0], _c1 = _cf[1], _c2 = _cf[2], _c3 = _cf[3];         \
    a0[0] += _c0 * _xx0; a0[1] += _c1 * _xx0;                             \
    a0[2] += _c2 * _xx0; a0[3] += _c3 * _xx0;                             \
    a1[0] += _c0 * _xx1; a1[1] += _c1 * _xx1;                             \
    a1[2] += _c2 * _xx1; a1[3] += _c3 * _xx1;                             \
} while (0)

// --- K3: FUSED aggregation + MFMA GEMM -------------------------------------
// Block = 16 nodes, 512 thr = 8 waves. Phase 1: dynamic node grab, 3-stage
// 16-deep fp8-gather pipeline over PADDED rows (no masks, exact batches).
// Phase 2: 16x1152 @ 1152x128 MFMA, 2-deep prefetch.
__global__ __launch_bounds__(512, 8) void k_fused(const uint8_t* __restrict__ xq,
                                                  const __hip_bfloat16* __restrict__ xb,
                                                  const float* __restrict__ comp17,
                                                  const int* __restrict__ rps,
                                                  const int* __restrict__ dga,
                                                  const int* __restrict__ csr,
                                                  const __hip_bfloat16* __restrict__ Wf,
                                                  const float* __restrict__ bias,
                                                  float* __restrict__ out, int M) {
    __shared__ __hip_bfloat16 fl[16][FPAD];
    __shared__ int snext;
    const uint16_t* __restrict__ xq16 = (const uint16_t*)xq;
    const uint32_t* __restrict__ xb32 = (const uint32_t*)xb;
    int t = threadIdx.x;
    int wid = t >> 6, lane = t & 63;
    int i0 = blockIdx.x * 16;
    if (t == 0) snext = 0;
    __syncthreads();

    // ---- phase 1: aggregate (dynamic node grab, scalar control plane) ----
    #pragma unroll 1
    while (true) {
        int grab = 0;
        if (lane == 0) grab = atomicAdd(&snext, 1);
        int lr = RFL(__shfl(grab, 0));
        if (lr >= 16) break;
        int iu = i0 + lr;                // uniform node id
        f32x2 a0[4], a1[4];              // [basis-pair] for ch0 / ch1
        #pragma unroll
        for (int b = 0; b < 4; b++) { a0[b] = (f32x2){0.f, 0.f}; a1[b] = (f32x2){0.f, 0.f}; }
        int s0 = 0, dg = 0;
        if (iu < M) {
            s0 = RFL(rps[iu]);
            dg = RFL(dga[iu]);
        }

        if (dg > 0) {                    // uniform branch
            int plen = (dg + 7) & ~7;
            int s1 = s0 + plen;
            int jj = s0;
            int p0 = RFL(csr[jj]),     p1 = RFL(csr[jj + 1]);
            int p2 = RFL(csr[jj + 2]), p3 = RFL(csr[jj + 3]);
            int p4 = RFL(csr[jj + 4]), p5 = RFL(csr[jj + 5]);
            int p6 = RFL(csr[jj + 6]), p7 = RFL(csr[jj + 7]);
            uint32_t w0 = GATH(p0), w1 = GATH(p1), w2 = GATH(p2), w3 = GATH(p3);
            uint32_t w4 = GATH(p4), w5 = GATH(p5), w6 = GATH(p6), w7 = GATH(p7);
            int q0 = RFL(csr[jj + 8]),  q1 = RFL(csr[jj + 9]);
            int q2 = RFL(csr[jj + 10]), q3 = RFL(csr[jj + 11]);
            int q4 = RFL(csr[jj + 12]), q5 = RFL(csr[jj + 13]);
            int q6 = RFL(csr[jj + 14]), q7 = RFL(csr[jj + 15]);
            uint32_t v0 = GATH(q0), v1 = GATH(q1), v2 = GATH(q2), v3 = GATH(q3);
            uint32_t v4 = GATH(q4), v5 = GATH(q5), v6 = GATH(q6), v7 = GATH(q7);

            #pragma unroll 1
            while (jj + 16 < s1) {
                int r0 = RFL(csr[jj + 16]), r1 = RFL(csr[jj + 17]);
                int r2 = RFL(csr[jj + 18]), r3 = RFL(csr[jj + 19]);
                int r4 = RFL(csr[jj + 20]), r5 = RFL(csr[jj + 21]);
                int r6 = RFL(csr[jj + 22]), r7 = RFL(csr[jj + 23]);
                uint32_t u0 = GATH(r0), u1 = GATH(r1), u2 = GATH(r2), u3 = GATH(r3);
                uint32_t u4 = GATH(r4), u5 = GATH(r5), u6 = GATH(r6), u7 = GATH(r7);
                CONS1(p0, w0); CONS1(p1, w1); CONS1(p2, w2); CONS1(p3, w3);
                CONS1(p4, w4); CONS1(p5, w5); CONS1(p6, w6); CONS1(p7, w7);
                p0 = q0; p1 = q1; p2 = q2; p3 = q3;
                p4 = q4; p5 = q5; p6 = q6; p7 = q7;
                w0 = v0; w1 = v1; w2 = v2; w3 = v3;
                w4 = v4; w5 = v5; w6 = v6; w7 = v7;
                q0 = r0; q1 = r1; q2 = r2; q3 = r3;
                q4 = r4; q5 = r5; q6 = r6; q7 = r7;
                v0 = u0; v1 = u1; v2 = u2; v3 = u3;
                v4 = u4; v5 = u5; v6 = u6; v7 = u7;
                jj += 8;
            }
            // exact tail: remaining is 8 or 16, no masks
            CONS1(p0, w0); CONS1(p1, w1); CONS1(p2, w2); CONS1(p3, w3);
            CONS1(p4, w4); CONS1(p5, w5); CONS1(p6, w6); CONS1(p7, w7);
            if (jj + 8 < s1) {           // uniform branch
                CONS1(q0, v0); CONS1(q1, v1); CONS1(q2, v2); CONS1(q3, v3);
                CONS1(q4, v4); CONS1(q5, v5); CONS1(q6, v6); CONS1(q7, v7);
            }
        }

        float inv = 1.0f / fmaxf((float)dg, 1.0f);
        #pragma unroll
        for (int b = 0; b < 8; b++) {
            __hip_bfloat16 h0 = __float2bfloat16(a0[b >> 1][b & 1] * inv);
            __hip_bfloat16 h1 = __float2bfloat16(a1[b >> 1][b & 1] * inv);
            uint32_t pk = ((uint32_t)*(uint16_t*)&h1 << 16) | *(uint16_t*)&h0;
            *(uint32_t*)&fl[lr][b * 128 + lane * 2] = pk;
        }
        uint32_t rr = (iu < M) ? xb32[(uint32_t)iu * 64u + lane] : 0u;
        *(uint32_t*)&fl[lr][1024 + lane * 2] = rr;
    }

    // ---- phase 2: MFMA, 2-deep prefetch; wave wid owns col-tile wid ----
    int lo = lane & 15, hi = lane >> 4;
    int wcol = wid * 16 + lo;
    const bf16x8* wv = (const bf16x8*)Wf;
    // B/bias don't depend on fl: issue before the barrier
    bf16x8 bA = wv[(hi << 7) + wcol];
    bf16x8 bB = wv[(((1 << 2) + hi) << 7) + wcol];
    float bs = bias[wcol];
    __syncthreads();

    f32x4 acc = (f32x4){0.f, 0.f, 0.f, 0.f};
    bf16x8 aA = *(const bf16x8*)&fl[lo][hi * 8];
    bf16x8 aB = *(const bf16x8*)&fl[lo][32 + hi * 8];
    #pragma unroll 4
    for (int kb = 0; kb < 34; kb++) {
        bf16x8 aN = *(const bf16x8*)&fl[lo][(kb + 2) * 32 + hi * 8];
        bf16x8 bN = wv[((((kb + 2) << 2) + hi) << 7) + wcol];
        acc = __builtin_amdgcn_mfma_f32_16x16x32_bf16(aA, bA, acc, 0, 0, 0);
        aA = aB; bA = bB; aB = aN; bB = bN;
    }
    acc = __builtin_amdgcn_mfma_f32_16x16x32_bf16(aA, bA, acc, 0, 0, 0);
    acc = __builtin_amdgcn_mfma_f32_16x16x32_bf16(aB, bB, acc, 0, 0, 0);

    #pragma unroll
    for (int q = 0; q < 4; q++) {
        int row = i0 + hi * 4 + q;   // C/D: col=lane&15, row=(lane>>4)*4+q
        if (row < M)
            out[(size_t)row * 128 + wcol] = acc[q] + bs;
    }
}

extern "C" void kernel_launch(void* const* d_in, const int* in_sizes, int n_in,
                              void* d_out, int out_size, void* d_ws, size_t ws_size,
                              hipStream_t stream) {
    const float* x      = (const float*)d_in[0];   // [N,128]
    const float* weight = (const float*)d_in[1];   // [9,128,128] = [1152,128]
    const float* comp   = (const float*)d_in[2];   // [16,8]
    const float* bias   = (const float*)d_in[3];   // [128]
    const int*   eidx   = (const int*)d_in[4];     // [2,E]
    const int*   etype  = (const int*)d_in[5];     // [E]

    int N = in_sizes[0] / 128;
    int E = in_sizes[5];
    const int* srcA = eidx;
    const int* dstA = eidx + E;
    int NB = (N + 127) >> 7;                       // buckets of 128 dsts

    uint8_t* ws = (uint8_t*)d_ws;
    size_t off = 0;
    auto take = [&](size_t bytes) -> void* {
        void* p = ws + off;
        off = (off + bytes + 255) & ~(size_t)255;
        return p;
    };
    uint8_t* xq        = (uint8_t*)take((size_t)N * 128);
    __hip_bfloat16* xb = (__hip_bfloat16*)take((size_t)N * 128 * sizeof(__hip_bfloat16));
    __hip_bfloat16* Wf = (__hip_bfloat16*)take((size_t)1152 * 128 * sizeof(__hip_bfloat16));
    float* comp17 = (float*)take(136 * sizeof(float));
    int* rps     = (int*)take((size_t)N * sizeof(int));
    int* dga     = (int*)take((size_t)N * sizeof(int));
    int* cursor  = (int*)take((size_t)NB * sizeof(int));
    int* brec    = (int*)take((size_t)NB * BKCAP * sizeof(int));
    int* csr     = (int*)take((size_t)NB * CSTRIDE * sizeof(int));
    (void)ws_size;

    int n4 = N * 128 / 4;
    int xbB = (n4 + 255) / 256;
    int wpB = (1152 * 128 + 255) / 256;
    int scB = (E + SCAT_CH - 1) / SCAT_CH;

    hipMemsetAsync(cursor, 0, (size_t)NB * sizeof(int), stream);
    k_ps<<<scB + xbB + wpB + 1, 256, 2 * NB * sizeof(int), stream>>>(
        x, xq, xb, n4, weight, Wf, comp, comp17,
        srcA, dstA, etype, E, NB, cursor, brec, scB, xbB, wpB);
    k_bsort<<<NB, 256, 0, stream>>>(brec, cursor, N, rps, dga, csr);
    k_fused<<<(N + 15) / 16, 512, 0, stream>>>(xq, xb, comp17, rps, dga, csr,
                                               Wf, bias, (float*)d_out, N);
}